// Round 21
// baseline (193.824 us; speedup 1.0000x reference)
//
#include <hip/hip_runtime.h>

// ---------------------------------------------------------------------------
// 2-layer GCN + LayerNorm on MI355X (gfx950), bf16 MFMA GEMMs.
//   Graph build (scatter-fill): deg64 = 0 (memset); k_fill_prep: one 64-bit
//   atomicAdd per edge packs {count:hi32, deg_16.16:lo32}; old>>32 = slot ->
//   csr[dst<<6|slot] = {ew_bf16|src_u16}. x->bf16 + W transposes hidden under
//   the atomic wall. k_deg: elementwise dinv/cnt.
//   LAYER-1 MEGAFUSION (k_agg_gemm): h2[i] = relu((A_norm@x)[i]@W1+b1)@W2 is
//   row-local after aggregation -> one kernel, block = 16 nodes / 4 waves:
//     p1: gather 4 nodes/wave (same 8-edge-unroll wall pattern) -> LDS axs
//     p2: out1 = axs @ W1T + b1, relu (R17 swapped-operand MFMA) -> LDS o1s
//     p3: h2 = o1s @ W2T -> global (axb/out1 never hit HBM; MFMA hides
//         under co-resident waves' gathers; LDS 12.8 KB -> 8 blocks/CU)
//   Then agg2_ln: out = LN(b2 + A_norm@h2) (gather wall, unchanged).
// ---------------------------------------------------------------------------

#define TPB 256
#define SLOT 64   // fixed CSR slots per node; P(deg>64) ~ 1e-20 for Poisson(16)

typedef __bf16 bf16;
typedef __bf16 bf16x2 __attribute__((ext_vector_type(2)));
typedef __bf16 bf16x4 __attribute__((ext_vector_type(4)));
typedef __bf16 bf16x8 __attribute__((ext_vector_type(8)));
typedef float  f32x4  __attribute__((ext_vector_type(4)));

// ---- fused: scatter-fill CSR (64b atomic: slot+deg) + x->bf16 + W^T -------
__global__ void k_fill_prep(const int* __restrict__ dst, const int* __restrict__ src,
                            const float* __restrict__ ew,
                            unsigned long long* deg64,
                            unsigned int* __restrict__ csr, int E,
                            const float* __restrict__ x, bf16* __restrict__ x_bf,
                            const float* __restrict__ W1, bf16* __restrict__ W1T,
                            const float* __restrict__ W2, bf16* __restrict__ W2T,
                            int n4, int nw, int D, int H) {
  int i = blockIdx.x * TPB + threadIdx.x;
  if (i < E) {
    int d = dst[i];
    float wf = ew[i];
    unsigned long long add =
        ((unsigned long long)1 << 32) |
        (unsigned long long)(unsigned int)(wf * 65536.0f + 0.5f);
    unsigned long long old = atomicAdd(&deg64[d], add);
    unsigned int pos = (unsigned int)(old >> 32);
    if (pos < SLOT) {
      unsigned int wb = __float_as_uint((float)(bf16)wf) & 0xFFFF0000u;
      csr[((size_t)d << 6) | pos] = wb | (unsigned int)src[i];   // src < 65536
    }
  }
  if (i < nw) {
    int r1 = i / H, c1 = i % H;          // W1 [D][H] -> W1T [H][D]
    W1T[(size_t)c1 * D + r1] = (bf16)W1[i];
    int r2 = i / D, c2 = i % D;          // W2 [H][D] -> W2T [D][H]
    W2T[(size_t)c2 * H + r2] = (bf16)W2[i];
  }
  if (i < n4) {
    float4 v = reinterpret_cast<const float4*>(x)[i];
    bf16x4 o;
    o.x = (bf16)v.x; o.y = (bf16)v.y; o.z = (bf16)v.z; o.w = (bf16)v.w;
    reinterpret_cast<bf16x4*>(x_bf)[i] = o;
  }
}

// ---- deg: elementwise dinv/cnt from packed deg64 --------------------------
__global__ void k_deg(const unsigned long long* __restrict__ deg64,
                      float* __restrict__ dinv, int* __restrict__ cnt, int N) {
  int i = blockIdx.x * TPB + threadIdx.x;
  if (i < N) {
    unsigned long long v = deg64[i];
    unsigned int c = (unsigned int)(v >> 32);
    float d = 1.0f + (float)(v & 0xFFFFFFFFull) * (1.0f / 65536.0f);
    dinv[i] = rsqrtf(d);
    cnt[i] = (c < SLOT) ? (int)c : SLOT;
  }
}

// per edge: w = ew * dinv[src]   (dinv lookup is wave-uniform broadcast)
#define UNPACK_EDGE(e, w, v)                                                   \
  float w = __uint_as_float((e) & 0xFFFF0000u) * dinv[(e) & 0xFFFFu];          \
  bf16x2 v = *reinterpret_cast<const bf16x2*>(h + (size_t)((e) & 0xFFFFu) * F + c2);

// ---- MEGAFUSED layer 1: gather(A_norm@x) -> @W1+b1,relu -> @W2 -> h2 ------
// Block: 256 thr / 4 waves / 16 nodes. LDS: axs[16][136], o1s[16][264] (+8
// pad -> 2-way bank conflicts only, rows 16B-aligned).
// MFMA (R17-verified swapped mfma(b,a)): lane l (c=l&15,g=l>>4):
//   a-frag = A[c][k0+8g..+7], b-frag = BT[n0+c][k0+8g..+7],
//   D: row = c, cols = n0+16ni+4g+r (r=0..3 consecutive).
__global__ __launch_bounds__(256) void k_agg_gemm(
    const bf16* __restrict__ h /*x_bf*/, const float* __restrict__ dinv,
    const int* __restrict__ cnt, const unsigned int* __restrict__ csr,
    const bf16* __restrict__ W1T, const float* __restrict__ b1,
    const bf16* __restrict__ W2T, bf16* __restrict__ h2, int N) {
  const int F = 128, H = 256;
  __shared__ bf16 axs[16][136];
  __shared__ bf16 o1s[16][264];
  const int wid = threadIdx.x >> 6, lane = threadIdx.x & 63;
  const int c = lane & 15, g = lane >> 4;
  const int c2 = lane << 1;

  // ---- phase 1: each wave gathers 4 nodes into axs rows ----
  for (int t = 0; t < 4; ++t) {
    int r = wid * 4 + t;
    int node = blockIdx.x * 16 + r;
    float ax = 0.f, ay = 0.f;
    if (node < N) {
      float di = dinv[node];
      bf16x2 hv = *reinterpret_cast<const bf16x2*>(h + (size_t)node * F + c2);
      float nx = 0.f, ny = 0.f;
      const unsigned int* cp = csr + ((size_t)node << 6);
      int n = cnt[node];
      int j = 0;
      for (; j + 8 <= n; j += 8) {
        uint4 q0 = *reinterpret_cast<const uint4*>(cp + j);
        uint4 q1 = *reinterpret_cast<const uint4*>(cp + j + 4);
        UNPACK_EDGE(q0.x, w0, v0) UNPACK_EDGE(q0.y, w1, v1)
        UNPACK_EDGE(q0.z, w2, v2) UNPACK_EDGE(q0.w, w3, v3)
        UNPACK_EDGE(q1.x, w4, v4) UNPACK_EDGE(q1.y, w5, v5)
        UNPACK_EDGE(q1.z, w6, v6) UNPACK_EDGE(q1.w, w7, v7)
        nx += w0 * (float)v0.x + w1 * (float)v1.x + w2 * (float)v2.x + w3 * (float)v3.x
            + w4 * (float)v4.x + w5 * (float)v5.x + w6 * (float)v6.x + w7 * (float)v7.x;
        ny += w0 * (float)v0.y + w1 * (float)v1.y + w2 * (float)v2.y + w3 * (float)v3.y
            + w4 * (float)v4.y + w5 * (float)v5.y + w6 * (float)v6.y + w7 * (float)v7.y;
      }
      for (; j < n; ++j) {
        unsigned int e = cp[j];
        UNPACK_EDGE(e, w, v)
        nx += w * (float)v.x; ny += w * (float)v.y;
      }
      float sw = di * di;
      ax = sw * (float)hv.x + di * nx;
      ay = sw * (float)hv.y + di * ny;
    }
    bf16x2 o; o.x = (bf16)ax; o.y = (bf16)ay;
    *reinterpret_cast<bf16x2*>(&axs[r][c2]) = o;
  }
  __syncthreads();

  // ---- phase 2: out1 strip (16 x 64 per wave) = axs @ W1T + b1, relu ----
  {
    f32x4 acc[4] = {};
    for (int k0 = 0; k0 < 128; k0 += 32) {
      bf16x8 a = *reinterpret_cast<const bf16x8*>(&axs[c][k0 + g * 8]);
#pragma unroll
      for (int ni = 0; ni < 4; ++ni) {
        int ncol = wid * 64 + ni * 16 + c;
        bf16x8 b = *reinterpret_cast<const bf16x8*>(W1T + (size_t)ncol * F + k0 + g * 8);
        acc[ni] = __builtin_amdgcn_mfma_f32_16x16x32_bf16(b, a, acc[ni], 0, 0, 0);
      }
    }
#pragma unroll
    for (int ni = 0; ni < 4; ++ni) {
      int col0 = wid * 64 + ni * 16 + g * 4;
      float4 bv = *reinterpret_cast<const float4*>(b1 + col0);
      f32x4 v = acc[ni];
      float o0 = fmaxf(v[0] + bv.x, 0.f), o1 = fmaxf(v[1] + bv.y, 0.f);
      float o2 = fmaxf(v[2] + bv.z, 0.f), o3 = fmaxf(v[3] + bv.w, 0.f);
      bf16x4 ob;
      ob.x = (bf16)o0; ob.y = (bf16)o1; ob.z = (bf16)o2; ob.w = (bf16)o3;
      *reinterpret_cast<bf16x4*>(&o1s[c][col0]) = ob;
    }
  }
  __syncthreads();

  // ---- phase 3: h2 strip (16 x 32 per wave) = o1s @ W2T ----
  {
    f32x4 acc[2] = {};
    for (int k0 = 0; k0 < 256; k0 += 32) {
      bf16x8 a = *reinterpret_cast<const bf16x8*>(&o1s[c][k0 + g * 8]);
#pragma unroll
      for (int ni = 0; ni < 2; ++ni) {
        int ncol = wid * 32 + ni * 16 + c;
        bf16x8 b = *reinterpret_cast<const bf16x8*>(W2T + (size_t)ncol * H + k0 + g * 8);
        acc[ni] = __builtin_amdgcn_mfma_f32_16x16x32_bf16(b, a, acc[ni], 0, 0, 0);
      }
    }
    int node = blockIdx.x * 16 + c;
    if (node < N) {
#pragma unroll
      for (int ni = 0; ni < 2; ++ni) {
        int col0 = wid * 32 + ni * 16 + g * 4;
        f32x4 v = acc[ni];
        bf16x4 ob;
        ob.x = (bf16)v[0]; ob.y = (bf16)v[1]; ob.z = (bf16)v[2]; ob.w = (bf16)v[3];
        *reinterpret_cast<bf16x4*>(h2 + (size_t)node * F + col0) = ob;
      }
    }
  }
}

// ---- agg layer 2 (bf16 in) + bias + fused LayerNorm, fp32 out -------------
__global__ __launch_bounds__(256) void k_agg2_ln(
    const bf16* __restrict__ h, const float* __restrict__ dinv,
    const int* __restrict__ cnt, const unsigned int* __restrict__ csr,
    const float* __restrict__ b2, const float* __restrict__ gamma,
    const float* __restrict__ beta, float* __restrict__ out, int N) {
  const int F = 128;
  int wid = threadIdx.x >> 6, lane = threadIdx.x & 63;
  int node = blockIdx.x * 4 + wid;
  if (node >= N) return;
  float di = dinv[node];
  int c2 = lane << 1;
  float2 bb = *reinterpret_cast<const float2*>(b2 + c2);
  bf16x2 hv = *reinterpret_cast<const bf16x2*>(h + (size_t)node * F + c2);
  float nx = 0.f, ny = 0.f;
  const unsigned int* cp = csr + ((size_t)node << 6);   // 256 B aligned
  int n = cnt[node];
  int j = 0;
  for (; j + 8 <= n; j += 8) {
    uint4 q0 = *reinterpret_cast<const uint4*>(cp + j);
    uint4 q1 = *reinterpret_cast<const uint4*>(cp + j + 4);
    UNPACK_EDGE(q0.x, w0, v0) UNPACK_EDGE(q0.y, w1, v1)
    UNPACK_EDGE(q0.z, w2, v2) UNPACK_EDGE(q0.w, w3, v3)
    UNPACK_EDGE(q1.x, w4, v4) UNPACK_EDGE(q1.y, w5, v5)
    UNPACK_EDGE(q1.z, w6, v6) UNPACK_EDGE(q1.w, w7, v7)
    nx += w0 * (float)v0.x + w1 * (float)v1.x + w2 * (float)v2.x + w3 * (float)v3.x
        + w4 * (float)v4.x + w5 * (float)v5.x + w6 * (float)v6.x + w7 * (float)v7.x;
    ny += w0 * (float)v0.y + w1 * (float)v1.y + w2 * (float)v2.y + w3 * (float)v3.y
        + w4 * (float)v4.y + w5 * (float)v5.y + w6 * (float)v6.y + w7 * (float)v7.y;
  }
  for (; j < n; ++j) {
    unsigned int e = cp[j];
    UNPACK_EDGE(e, w, v)
    nx += w * (float)v.x; ny += w * (float)v.y;
  }
  float sw = di * di;
  float ax = bb.x + sw * (float)hv.x + di * nx;
  float ay = bb.y + sw * (float)hv.y + di * ny;
  // LayerNorm across the wave (128 values = 64 lanes x 2)
  float s  = ax + ay;
  float ss = ax * ax + ay * ay;
  for (int m = 32; m > 0; m >>= 1) {
    s  += __shfl_xor(s, m, 64);
    ss += __shfl_xor(ss, m, 64);
  }
  float mu  = s * (1.0f / 128.0f);
  float var = ss * (1.0f / 128.0f) - mu * mu;
  float inv = rsqrtf(var + 1e-5f);
  float2 g  = *reinterpret_cast<const float2*>(gamma + c2);
  float2 be = *reinterpret_cast<const float2*>(beta + c2);
  float2 o;
  o.x = (ax - mu) * inv * g.x + be.x;
  o.y = (ay - mu) * inv * g.y + be.y;
  *reinterpret_cast<float2*>(out + (size_t)node * F + c2) = o;
}

extern "C" void kernel_launch(void* const* d_in, const int* in_sizes, int n_in,
                              void* d_out, int out_size, void* d_ws, size_t ws_size,
                              hipStream_t stream) {
  const float* x     = (const float*)d_in[0];
  const int*   ei    = (const int*)d_in[1];
  const float* ew    = (const float*)d_in[2];
  const float* W1    = (const float*)d_in[3];
  const float* b1    = (const float*)d_in[4];
  const float* W2    = (const float*)d_in[5];
  const float* b2    = (const float*)d_in[6];
  const float* gamma = (const float*)d_in[7];
  const float* beta  = (const float*)d_in[8];
  float* out = (float*)d_out;

  const int D = 128, H = 256;
  const int N = in_sizes[0] / D;       // 50000
  const int E = in_sizes[2];           // 800000
  const int* src = ei;
  const int* dst = ei + E;

  // workspace carve-up (256B aligned)
  char* p = (char*)d_ws;
  auto carve = [&](size_t bytes) -> void* {
    void* r = (void*)p;
    p += (bytes + 255) & ~(size_t)255;
    return r;
  };
  float*              dinv  = (float*)carve((size_t)N * 4);
  int*                cnt   = (int*)  carve((size_t)N * 4);
  unsigned long long* deg64 = (unsigned long long*)carve((size_t)N * 8);
  unsigned int*       csr   = (unsigned int*)carve((size_t)N * SLOT * 4);
  bf16*               x_bf  = (bf16*) carve((size_t)N * D * 2);
  bf16*               h2    = (bf16*) carve((size_t)N * D * 2);
  bf16*               W1T   = (bf16*) carve((size_t)D * H * 2);
  bf16*               W2T   = (bf16*) carve((size_t)H * D * 2);

  const int gN = (N + TPB - 1) / TPB;
  const int n4 = N * D / 4;
  const int nw = D * H;
  const int gE = (E + TPB - 1) / TPB;
  const int gP = (n4 + TPB - 1) / TPB;
  const int gF = (gE > gP) ? gE : gP;   // fused fill+prep grid

  hipMemsetAsync(deg64, 0, (size_t)N * 8, stream);
  k_fill_prep<<<gF, TPB, 0, stream>>>(dst, src, ew, deg64, csr, E,
                                      x, x_bf, W1, W1T, W2, W2T, n4, nw, D, H);
  k_deg<<<gN, TPB, 0, stream>>>(deg64, dinv, cnt, N);

  // layer 1 megafused: gather -> @W1+b1,relu -> @W2 -> h2
  k_agg_gemm<<<(N + 15) / 16, TPB, 0, stream>>>(x_bf, dinv, cnt, csr,
                                                W1T, b1, W2T, h2, N);

  // layer 2: agg + bias + fused LN (fp32 out)
  k_agg2_ln<<<(N + 3) / 4, TPB, 0, stream>>>(h2, dinv, cnt, csr,
                                             b2, gamma, beta, out, N);
}

// Round 22
// 179.608 us; speedup vs baseline: 1.0791x; 1.0791x over previous
//
#include <hip/hip_runtime.h>

// ---------------------------------------------------------------------------
// 2-layer GCN + LayerNorm on MI355X (gfx950), bf16 MFMA GEMMs.
//   Graph build (scatter-fill): deg64 = 0 (memset); k_fill_prep: one 64-bit
//   atomicAdd per edge packs {count:hi32, deg_16.16:lo32}; old>>32 = slot ->
//   csr[dst<<6|slot] = {ew_bf16|src_u16}. x->bf16 + W transposes hidden under
//   the atomic wall (~18 G atomics/s). k_deg: elementwise dinv/cnt.
//   Layer 1: k_agg_x (gather wall, one wave/node -- R21 lesson: never
//   serialize multiple gathers per wave), then k_gemm12 fuses BOTH GEMMs:
//     phase A: out1 tile (128x256) = axb @ W1T + b1, relu -> LDS (66 KB)
//     phase B: h2 (128x128) = out1_tile @ W2T -> global
//   out1 never touches memory; axb read exactly once (12.8 MB total).
//   Layer 2: agg2_ln = LN(b2 + A_norm@h2) (gather wall, unchanged).
//   MFMA everywhere: R17-verified swapped-operand mfma(b,a): lane l
//   (c=l&15, g=l>>4): row = c(+16mi+32w), cols = 16ni+4g+r consecutive ->
//   bf16x4 vector stores.
// ---------------------------------------------------------------------------

#define TPB 256
#define SLOT 64   // fixed CSR slots per node; P(deg>64) ~ 1e-20 for Poisson(16)

typedef __bf16 bf16;
typedef __bf16 bf16x2 __attribute__((ext_vector_type(2)));
typedef __bf16 bf16x4 __attribute__((ext_vector_type(4)));
typedef __bf16 bf16x8 __attribute__((ext_vector_type(8)));
typedef float  f32x4  __attribute__((ext_vector_type(4)));

// ---- fused: scatter-fill CSR (64b atomic: slot+deg) + x->bf16 + W^T -------
__global__ void k_fill_prep(const int* __restrict__ dst, const int* __restrict__ src,
                            const float* __restrict__ ew,
                            unsigned long long* deg64,
                            unsigned int* __restrict__ csr, int E,
                            const float* __restrict__ x, bf16* __restrict__ x_bf,
                            const float* __restrict__ W1, bf16* __restrict__ W1T,
                            const float* __restrict__ W2, bf16* __restrict__ W2T,
                            int n4, int nw, int D, int H) {
  int i = blockIdx.x * TPB + threadIdx.x;
  if (i < E) {
    int d = dst[i];
    float wf = ew[i];
    unsigned long long add =
        ((unsigned long long)1 << 32) |
        (unsigned long long)(unsigned int)(wf * 65536.0f + 0.5f);
    unsigned long long old = atomicAdd(&deg64[d], add);
    unsigned int pos = (unsigned int)(old >> 32);
    if (pos < SLOT) {
      unsigned int wb = __float_as_uint((float)(bf16)wf) & 0xFFFF0000u;
      csr[((size_t)d << 6) | pos] = wb | (unsigned int)src[i];   // src < 65536
    }
  }
  if (i < nw) {
    int r1 = i / H, c1 = i % H;          // W1 [D][H] -> W1T [H][D]
    W1T[(size_t)c1 * D + r1] = (bf16)W1[i];
    int r2 = i / D, c2 = i % D;          // W2 [H][D] -> W2T [D][H]
    W2T[(size_t)c2 * H + r2] = (bf16)W2[i];
  }
  if (i < n4) {
    float4 v = reinterpret_cast<const float4*>(x)[i];
    bf16x4 o;
    o.x = (bf16)v.x; o.y = (bf16)v.y; o.z = (bf16)v.z; o.w = (bf16)v.w;
    reinterpret_cast<bf16x4*>(x_bf)[i] = o;
  }
}

// ---- deg: elementwise dinv/cnt from packed deg64 --------------------------
__global__ void k_deg(const unsigned long long* __restrict__ deg64,
                      float* __restrict__ dinv, int* __restrict__ cnt, int N) {
  int i = blockIdx.x * TPB + threadIdx.x;
  if (i < N) {
    unsigned long long v = deg64[i];
    unsigned int c = (unsigned int)(v >> 32);
    float d = 1.0f + (float)(v & 0xFFFFFFFFull) * (1.0f / 65536.0f);
    dinv[i] = rsqrtf(d);
    cnt[i] = (c < SLOT) ? (int)c : SLOT;
  }
}

// per edge: w = ew * dinv[src]   (dinv lookup is wave-uniform broadcast)
#define UNPACK_EDGE(e, w, v)                                                   \
  float w = __uint_as_float((e) & 0xFFFF0000u) * dinv[(e) & 0xFFFFu];          \
  bf16x2 v = *reinterpret_cast<const bf16x2*>(h + (size_t)((e) & 0xFFFFu) * F + c2);

// ---- agg layer 1: F=128 bf16 rows, one wave/node, 8-edge unroll -----------
__global__ __launch_bounds__(256) void k_agg_x(
    const bf16* __restrict__ h, const float* __restrict__ dinv,
    const int* __restrict__ cnt, const unsigned int* __restrict__ csr,
    bf16* __restrict__ out, int N) {
  const int F = 128;
  int wid = threadIdx.x >> 6, lane = threadIdx.x & 63;
  int node = blockIdx.x * 4 + wid;
  if (node >= N) return;
  float di = dinv[node];
  int c2 = lane << 1;
  bf16x2 hv = *reinterpret_cast<const bf16x2*>(h + (size_t)node * F + c2);
  float nx = 0.f, ny = 0.f;   // neighbor sum (pre-dinv_d)
  const unsigned int* cp = csr + ((size_t)node << 6);   // 256 B aligned
  int n = cnt[node];
  int j = 0;
  for (; j + 8 <= n; j += 8) {
    uint4 q0 = *reinterpret_cast<const uint4*>(cp + j);
    uint4 q1 = *reinterpret_cast<const uint4*>(cp + j + 4);
    UNPACK_EDGE(q0.x, w0, v0) UNPACK_EDGE(q0.y, w1, v1)
    UNPACK_EDGE(q0.z, w2, v2) UNPACK_EDGE(q0.w, w3, v3)
    UNPACK_EDGE(q1.x, w4, v4) UNPACK_EDGE(q1.y, w5, v5)
    UNPACK_EDGE(q1.z, w6, v6) UNPACK_EDGE(q1.w, w7, v7)
    nx += w0 * (float)v0.x + w1 * (float)v1.x + w2 * (float)v2.x + w3 * (float)v3.x
        + w4 * (float)v4.x + w5 * (float)v5.x + w6 * (float)v6.x + w7 * (float)v7.x;
    ny += w0 * (float)v0.y + w1 * (float)v1.y + w2 * (float)v2.y + w3 * (float)v3.y
        + w4 * (float)v4.y + w5 * (float)v5.y + w6 * (float)v6.y + w7 * (float)v7.y;
  }
  for (; j < n; ++j) {
    unsigned int e = cp[j];
    UNPACK_EDGE(e, w, v)
    nx += w * (float)v.x; ny += w * (float)v.y;
  }
  float sw = di * di;
  float ax = sw * (float)hv.x + di * nx;
  float ay = sw * (float)hv.y + di * ny;
  bf16x2 o; o.x = (bf16)ax; o.y = (bf16)ay;
  *reinterpret_cast<bf16x2*>(out + (size_t)node * F + c2) = o;
}

// ---- fused GEMM-GEMM: h2 = relu(axb @ W1T + b1) @ W2T ---------------------
// Block: 256 thr / 4 waves / 128 rows; grid 391. LDS out1 tile 128x264 (pad
// 8 -> 132-dword row stride -> 2-way bank conflicts only, free).
__global__ __launch_bounds__(256) void k_gemm12(
    const bf16* __restrict__ A /*axb [M,128]*/,
    const bf16* __restrict__ W1T /*[256][128]*/, const float* __restrict__ b1,
    const bf16* __restrict__ W2T /*[128][256]*/,
    bf16* __restrict__ h2 /*[M,128]*/, int M) {
  const int D = 128, H = 256;
  __shared__ bf16 o1s[128][264];
  const int l = threadIdx.x & 63, w = threadIdx.x >> 6;
  const int c = l & 15, g = l >> 4;
  const int m0 = blockIdx.x * 128 + w * 32;

  // ---- phase A: out1 tile = A @ W1T + b1, relu -> LDS ----
  {
    int ra0 = m0 + c;       if (ra0 >= M) ra0 = M - 1;
    int ra1 = m0 + 16 + c;  if (ra1 >= M) ra1 = M - 1;
    const bf16* pa0 = A + (size_t)ra0 * D + g * 8;
    const bf16* pa1 = A + (size_t)ra1 * D + g * 8;
#pragma unroll
    for (int pass = 0; pass < 2; ++pass) {
      const int n0 = pass * 128;
      f32x4 acc[2][8] = {};
      for (int k0 = 0; k0 < D; k0 += 32) {
        bf16x8 a0 = *reinterpret_cast<const bf16x8*>(pa0 + k0);
        bf16x8 a1 = *reinterpret_cast<const bf16x8*>(pa1 + k0);
#pragma unroll
        for (int ni = 0; ni < 8; ++ni) {
          const bf16* pb = W1T + (size_t)(n0 + ni * 16 + c) * D + k0 + g * 8;
          bf16x8 b = *reinterpret_cast<const bf16x8*>(pb);
          acc[0][ni] = __builtin_amdgcn_mfma_f32_16x16x32_bf16(b, a0, acc[0][ni], 0, 0, 0);
          acc[1][ni] = __builtin_amdgcn_mfma_f32_16x16x32_bf16(b, a1, acc[1][ni], 0, 0, 0);
        }
      }
#pragma unroll
      for (int mi = 0; mi < 2; ++mi) {
        int lrow = w * 32 + mi * 16 + c;
#pragma unroll
        for (int ni = 0; ni < 8; ++ni) {
          int col0 = n0 + ni * 16 + g * 4;
          float4 bv = *reinterpret_cast<const float4*>(b1 + col0);
          f32x4 v = acc[mi][ni];
          float o0 = fmaxf(v[0] + bv.x, 0.f), o1 = fmaxf(v[1] + bv.y, 0.f);
          float o2 = fmaxf(v[2] + bv.z, 0.f), o3 = fmaxf(v[3] + bv.w, 0.f);
          bf16x4 ob;
          ob.x = (bf16)o0; ob.y = (bf16)o1; ob.z = (bf16)o2; ob.w = (bf16)o3;
          *reinterpret_cast<bf16x4*>(&o1s[lrow][col0]) = ob;
        }
      }
    }
  }
  __syncthreads();

  // ---- phase B: h2 rows = out1_tile @ W2T (K=256) ----
  {
    f32x4 acc[2][8] = {};
    for (int k0 = 0; k0 < H; k0 += 32) {
      bf16x8 a0 = *reinterpret_cast<const bf16x8*>(&o1s[w * 32 + c][k0 + g * 8]);
      bf16x8 a1 = *reinterpret_cast<const bf16x8*>(&o1s[w * 32 + 16 + c][k0 + g * 8]);
#pragma unroll
      for (int ni = 0; ni < 8; ++ni) {
        const bf16* pb = W2T + (size_t)(ni * 16 + c) * H + k0 + g * 8;
        bf16x8 b = *reinterpret_cast<const bf16x8*>(pb);
        acc[0][ni] = __builtin_amdgcn_mfma_f32_16x16x32_bf16(b, a0, acc[0][ni], 0, 0, 0);
        acc[1][ni] = __builtin_amdgcn_mfma_f32_16x16x32_bf16(b, a1, acc[1][ni], 0, 0, 0);
      }
    }
#pragma unroll
    for (int mi = 0; mi < 2; ++mi) {
      int row = m0 + mi * 16 + c;
      if (row < M) {
#pragma unroll
        for (int ni = 0; ni < 8; ++ni) {
          int col0 = ni * 16 + g * 4;
          f32x4 v = acc[mi][ni];
          bf16x4 ob;
          ob.x = (bf16)v[0]; ob.y = (bf16)v[1]; ob.z = (bf16)v[2]; ob.w = (bf16)v[3];
          *reinterpret_cast<bf16x4*>(h2 + (size_t)row * D + col0) = ob;
        }
      }
    }
  }
}

// ---- agg layer 2 (bf16 in) + bias + fused LayerNorm, fp32 out -------------
__global__ __launch_bounds__(256) void k_agg2_ln(
    const bf16* __restrict__ h, const float* __restrict__ dinv,
    const int* __restrict__ cnt, const unsigned int* __restrict__ csr,
    const float* __restrict__ b2, const float* __restrict__ gamma,
    const float* __restrict__ beta, float* __restrict__ out, int N) {
  const int F = 128;
  int wid = threadIdx.x >> 6, lane = threadIdx.x & 63;
  int node = blockIdx.x * 4 + wid;
  if (node >= N) return;
  float di = dinv[node];
  int c2 = lane << 1;
  float2 bb = *reinterpret_cast<const float2*>(b2 + c2);
  bf16x2 hv = *reinterpret_cast<const bf16x2*>(h + (size_t)node * F + c2);
  float nx = 0.f, ny = 0.f;
  const unsigned int* cp = csr + ((size_t)node << 6);   // 256 B aligned
  int n = cnt[node];
  int j = 0;
  for (; j + 8 <= n; j += 8) {
    uint4 q0 = *reinterpret_cast<const uint4*>(cp + j);
    uint4 q1 = *reinterpret_cast<const uint4*>(cp + j + 4);
    UNPACK_EDGE(q0.x, w0, v0) UNPACK_EDGE(q0.y, w1, v1)
    UNPACK_EDGE(q0.z, w2, v2) UNPACK_EDGE(q0.w, w3, v3)
    UNPACK_EDGE(q1.x, w4, v4) UNPACK_EDGE(q1.y, w5, v5)
    UNPACK_EDGE(q1.z, w6, v6) UNPACK_EDGE(q1.w, w7, v7)
    nx += w0 * (float)v0.x + w1 * (float)v1.x + w2 * (float)v2.x + w3 * (float)v3.x
        + w4 * (float)v4.x + w5 * (float)v5.x + w6 * (float)v6.x + w7 * (float)v7.x;
    ny += w0 * (float)v0.y + w1 * (float)v1.y + w2 * (float)v2.y + w3 * (float)v3.y
        + w4 * (float)v4.y + w5 * (float)v5.y + w6 * (float)v6.y + w7 * (float)v7.y;
  }
  for (; j < n; ++j) {
    unsigned int e = cp[j];
    UNPACK_EDGE(e, w, v)
    nx += w * (float)v.x; ny += w * (float)v.y;
  }
  float sw = di * di;
  float ax = bb.x + sw * (float)hv.x + di * nx;
  float ay = bb.y + sw * (float)hv.y + di * ny;
  // LayerNorm across the wave (128 values = 64 lanes x 2)
  float s  = ax + ay;
  float ss = ax * ax + ay * ay;
  for (int m = 32; m > 0; m >>= 1) {
    s  += __shfl_xor(s, m, 64);
    ss += __shfl_xor(ss, m, 64);
  }
  float mu  = s * (1.0f / 128.0f);
  float var = ss * (1.0f / 128.0f) - mu * mu;
  float inv = rsqrtf(var + 1e-5f);
  float2 g  = *reinterpret_cast<const float2*>(gamma + c2);
  float2 be = *reinterpret_cast<const float2*>(beta + c2);
  float2 o;
  o.x = (ax - mu) * inv * g.x + be.x;
  o.y = (ay - mu) * inv * g.y + be.y;
  *reinterpret_cast<float2*>(out + (size_t)node * F + c2) = o;
}

extern "C" void kernel_launch(void* const* d_in, const int* in_sizes, int n_in,
                              void* d_out, int out_size, void* d_ws, size_t ws_size,
                              hipStream_t stream) {
  const float* x     = (const float*)d_in[0];
  const int*   ei    = (const int*)d_in[1];
  const float* ew    = (const float*)d_in[2];
  const float* W1    = (const float*)d_in[3];
  const float* b1    = (const float*)d_in[4];
  const float* W2    = (const float*)d_in[5];
  const float* b2    = (const float*)d_in[6];
  const float* gamma = (const float*)d_in[7];
  const float* beta  = (const float*)d_in[8];
  float* out = (float*)d_out;

  const int D = 128, H = 256;
  const int N = in_sizes[0] / D;       // 50000
  const int E = in_sizes[2];           // 800000
  const int* src = ei;
  const int* dst = ei + E;

  // workspace carve-up (256B aligned)
  char* p = (char*)d_ws;
  auto carve = [&](size_t bytes) -> void* {
    void* r = (void*)p;
    p += (bytes + 255) & ~(size_t)255;
    return r;
  };
  float*              dinv  = (float*)carve((size_t)N * 4);
  int*                cnt   = (int*)  carve((size_t)N * 4);
  unsigned long long* deg64 = (unsigned long long*)carve((size_t)N * 8);
  unsigned int*       csr   = (unsigned int*)carve((size_t)N * SLOT * 4);
  bf16*               x_bf  = (bf16*) carve((size_t)N * D * 2);
  bf16*               axb   = (bf16*) carve((size_t)N * D * 2);
  bf16*               h2    = (bf16*) carve((size_t)N * D * 2);
  bf16*               W1T   = (bf16*) carve((size_t)D * H * 2);
  bf16*               W2T   = (bf16*) carve((size_t)H * D * 2);

  const int gN = (N + TPB - 1) / TPB;
  const int n4 = N * D / 4;
  const int nw = D * H;
  const int gE = (E + TPB - 1) / TPB;
  const int gP = (n4 + TPB - 1) / TPB;
  const int gF = (gE > gP) ? gE : gP;   // fused fill+prep grid

  hipMemsetAsync(deg64, 0, (size_t)N * 8, stream);
  k_fill_prep<<<gF, TPB, 0, stream>>>(dst, src, ew, deg64, csr, E,
                                      x, x_bf, W1, W1T, W2, W2T, n4, nw, D, H);
  k_deg<<<gN, TPB, 0, stream>>>(deg64, dinv, cnt, N);

  // layer 1: aggregate-first, then fused GEMM-GEMM (out1 stays in LDS)
  k_agg_x<<<(N + 3) / 4, TPB, 0, stream>>>(x_bf, dinv, cnt, csr, axb, N);
  k_gemm12<<<(N + 127) / 128, TPB, 0, stream>>>(axb, W1T, b1, W2T, h2, N);

  // layer 2: agg + bias + fused LN (fp32 out)
  k_agg2_ln<<<(N + 3) / 4, TPB, 0, stream>>>(h2, dinv, cnt, csr,
                                             b2, gamma, beta, out, N);
}